// Round 5
// baseline (3269.681 us; speedup 1.0000x reference)
//
#include <hip/hip_runtime.h>
#include <cstdint>

// Problem constants (from reference)
#define VN 100000   // vocab
#define DD 128      // D
#define BB 512      // batch
#define LL 20       // session length
#define TT 20       // time steps
#define HH 32       // H
#define CC 33       // C = H+1
#define NC (HH*CC)  // 1056

typedef unsigned int u32;

#define DEV static __device__ __forceinline__

DEV float tanh_fast(float x){ float e=__expf(2.f*x); return 1.f - 2.f/(e+1.f); }

// ================= K1: fused knots + CDE RK4 scan (G=4 rows/block) =========
// LDS kept < 64 KB via phase union:
//   phase 1 (knot build): s_er (40 emb rows, 20KB) + s_rw (16.5KB)
//   phase 2 (RK4 scan):   s_w1t (16KB)
__global__ __launch_bounds__(256) void k_cde(
    const float* __restrict__ emb, const int* __restrict__ eids,
    const float* __restrict__ times,
    const float* __restrict__ red_w, const float* __restrict__ red_b,
    const float* __restrict__ w1, const float* __restrict__ b1,
    const float* __restrict__ w2, const float* __restrict__ b2,
    const float* __restrict__ iw, const float* __restrict__ ib,
    const float* __restrict__ rw, const float* __restrict__ rb,
    float* __restrict__ te){
  __shared__ float s_u[5120+4128];    // union: [er 40*128 | rw 32*129] / [w1t 32*128]
  __shared__ float s_X[4*TT*CC];      // [g][t][c] (10.6 KB), persistent
  __shared__ float s_b1[DD];
  __shared__ float s_b2[NC];
  __shared__ float s_h1[4*DD];
  __shared__ float s_z[4*HH], s_zs[4*HH], s_ks[4*HH];
  __shared__ float s_dx[4*CC];
  float* s_er  = s_u;                 // phase 1
  float* s_rw  = s_u + 5120;          // phase 1 (padded rows: DD+1)
  float* s_w1t = s_u;                 // phase 2
  const int t = threadIdx.x;
  const int b0 = blockIdx.x*4;

  // ---- phase-1 weights
  for(int i=t;i<HH*DD;i+=256){ int h=i>>7,d=i&127; s_rw[h*(DD+1)+d]=red_w[i]; }
  for(int i=t;i<DD;i+=256) s_b1[i]=b1[i];
  for(int i=t;i<NC;i+=256) s_b2[i]=b2[i];
  // ---- X[...,0] = times
  if(t<80){ int g=t/TT, tt2=t%TT;
    s_X[(g*TT+tt2)*CC]=times[(b0+g)*TT+tt2]; }
  // ---- fode = l2n(emb_row @ red_w.T + red_b) into X[...,1+h], in 2 halves
  for(int half=0; half<2; half++){
    __syncthreads();                  // prev-half readers done before overwrite
    for(int p=t;p<40*DD;p+=256){      // load 40 knot emb rows
      int r=p>>7, e=p&127;
      s_er[p]=emb[(size_t)eids[b0*TT+half*40+r]*DD+e];
    }
    __syncthreads();
    for(int task=t; task<40*HH; task+=256){
      int r=task>>5, h=task&31;
      const float* wr=s_rw+h*(DD+1);
      const float* er=s_er+r*DD;
      float acc=red_b[h];
      #pragma unroll 16
      for(int e=0;e<DD;e++) acc += er[e]*wr[e];
      float s=acc*acc;
      #pragma unroll
      for(int o=16;o>0;o>>=1) s+=__shfl_xor(s,o,32);
      int rg=half*40+r;               // global knot index 0..79
      int g=rg/TT, tt2=rg%TT;
      s_X[(g*TT+tt2)*CC+1+h]=acc/(sqrtf(s)+1e-12f);
    }
  }
  __syncthreads();                    // fode done; union now free
  // ---- phase-2: w1 transposed into the union
  for(int i=t;i<HH*DD;i+=256){ int r=i>>5,h=i&31; s_w1t[h*DD+r]=w1[i]; }
  // ---- z0 = X[:,0] @ init_w.T + init_b
  if(t<128){
    int g=t>>5, h=t&31;
    float acc=ib[h];
    const float* x0=s_X+(size_t)(g*TT)*CC;
    #pragma unroll
    for(int c=0;c<CC;c++) acc += x0[c]*iw[h*CC+c];
    s_z[g*HH+h]=acc; s_zs[g*HH+h]=acc;
  }
  // ---- stage-B thread mapping: (h_b, qc) -> c-slice
  const int h_b = t>>3;                     // 0..31
  const int qc  = t&7;                      // 0..7
  const int c0  = (qc==0)?0:(5+(qc-1)*4);
  const int ncr = (qc==0)?5:4;
  const int n0  = h_b*CC + c0;              // w2 row base (row n = h*C + c)
  const float4* w2v=(const float4*)w2;      // 32 float4 / row

  for(int step=0; step<TT-1; step++){
    __syncthreads();
    if(t<4*CC){                             // dx for this step
      int g=t/CC, c=t-g*CC;
      s_dx[g*CC+c]=s_X[(g*TT+step+1)*CC+c]-s_X[(g*TT+step)*CC+c];
    }
    for(int s=0;s<4;s++){
      __syncthreads();
      { // stage A: h1 = relu(zs @ w1.T + b1), 4x128
        int g=t>>7, i=t&127;
        float a0=s_b1[i], a1=a0;
        #pragma unroll
        for(int h=0;h<HH;h++){
          float wv=s_w1t[h*DD+i];
          a0 += s_zs[g*HH+h]*wv;
          a1 += s_zs[(g+2)*HH+h]*wv;
        }
        s_h1[g*DD+i]=fmaxf(a0,0.f);
        s_h1[(g+2)*DD+i]=fmaxf(a1,0.f);
      }
      __syncthreads();
      // stage B: o2 = h1 @ w2.T + b2 ; k = sum_c tanh(o2)[h,c]*dx[c]
      float pk0=0.f,pk1=0.f,pk2=0.f,pk3=0.f;
      {
        float acc[5][4];
        #pragma unroll
        for(int r=0;r<5;r++){
          #pragma unroll
          for(int g=0;g<4;g++) acc[r][g]=0.f;
        }
        const float4* h4=(const float4*)s_h1;
        for(int j=0;j<16;j++){
          float hv[4][8];
          #pragma unroll
          for(int g=0;g<4;g++){
            float4 va=h4[g*32+j*2];
            float4 vb=h4[g*32+j*2+1];
            hv[g][0]=va.x; hv[g][1]=va.y; hv[g][2]=va.z; hv[g][3]=va.w;
            hv[g][4]=vb.x; hv[g][5]=vb.y; hv[g][6]=vb.z; hv[g][7]=vb.w;
          }
          #pragma unroll
          for(int r=0;r<5;r++){
            if(r<ncr){
              float4 ua=w2v[(size_t)(n0+r)*32+j*2];
              float4 ub=w2v[(size_t)(n0+r)*32+j*2+1];
              float wf[8];
              wf[0]=ua.x; wf[1]=ua.y; wf[2]=ua.z; wf[3]=ua.w;
              wf[4]=ub.x; wf[5]=ub.y; wf[6]=ub.z; wf[7]=ub.w;
              #pragma unroll
              for(int k=0;k<8;k++){
                float wk=wf[k];
                acc[r][0]+=wk*hv[0][k];
                acc[r][1]+=wk*hv[1][k];
                acc[r][2]+=wk*hv[2][k];
                acc[r][3]+=wk*hv[3][k];
              }
            }
          }
        }
        #pragma unroll
        for(int r=0;r<5;r++){
          if(r<ncr){
            int c=c0+r;
            float bb2=s_b2[n0+r];
            pk0 += tanh_fast(acc[r][0]+bb2)*s_dx[c];
            pk1 += tanh_fast(acc[r][1]+bb2)*s_dx[CC+c];
            pk2 += tanh_fast(acc[r][2]+bb2)*s_dx[2*CC+c];
            pk3 += tanh_fast(acc[r][3]+bb2)*s_dx[3*CC+c];
          }
        }
      }
      #pragma unroll
      for(int o=4;o>0;o>>=1){
        pk0 += __shfl_xor(pk0,o,8);
        pk1 += __shfl_xor(pk1,o,8);
        pk2 += __shfl_xor(pk2,o,8);
        pk3 += __shfl_xor(pk3,o,8);
      }
      if((t&7)==0){  // RK4 bookkeeping: one thread per h, all 4 g
        int h=t>>3;
        float pk[4]={pk0,pk1,pk2,pk3};
        #pragma unroll
        for(int g=0;g<4;g++){
          int idx=g*HH+h;
          float k=pk[g], zv=s_z[idx];
          if(s==0){ s_ks[idx]=k;        s_zs[idx]=zv+0.5f*k; }
          else if(s==1){ s_ks[idx]+=2.f*k; s_zs[idx]=zv+0.5f*k; }
          else if(s==2){ s_ks[idx]+=2.f*k; s_zs[idx]=zv+k; }
          else { float zn=zv+(s_ks[idx]+k)*(1.f/6.f); s_z[idx]=zn; s_zs[idx]=zn; }
        }
      }
    }
  }
  __syncthreads();
  { // time_embeds = zT @ rec_w.T + rec_b
    int g2=t>>7, d=t&127;
    #pragma unroll
    for(int gg=0; gg<2; gg++){
      int g=g2+2*gg;
      float acc=rb[d];
      #pragma unroll
      for(int h=0;h<HH;h++) acc += s_z[g*HH+h]*rw[d*HH+h];
      te[(size_t)(b0+g)*DD+d]=acc;
    }
  }
}

// ================= K2: attention readout + sr (featn recomputed) ===========
__global__ __launch_bounds__(128) void k_attn(
    const float* __restrict__ emb, const int* __restrict__ iid,
    const int* __restrict__ last_nodes,
    const float* __restrict__ fcu_w, const float* __restrict__ fcv_w,
    const float* __restrict__ fcv_b, const float* __restrict__ fce_w,
    const float* __restrict__ fcsr_w,
    const float* __restrict__ te, float* __restrict__ sr){
  __shared__ float s_fn[LL*DD];      // featn tile = x/||x||
  __shared__ float s_inv[LL];
  __shared__ float s_e[LL], s_alpha[LL], s_red[2], s_sg[DD], s_fl[DD];
  const int t=threadIdx.x, b=blockIdx.x;
  for(int p=t;p<LL*DD;p+=128){
    int r=p>>7, e=p&127;
    s_fn[p]=emb[(size_t)iid[b*LL+r]*DD+e];
  }
  __syncthreads();
  { int w=t>>6, lane=t&63;
    for(int r=w;r<LL;r+=2){
      float a=s_fn[r*DD+lane], c=s_fn[r*DD+lane+64];
      float s=a*a+c*c;
      #pragma unroll
      for(int o=32;o>0;o>>=1) s+=__shfl_xor(s,o,64);
      if(lane==0) s_inv[r]=1.f/sqrtf(s);
    }
  }
  __syncthreads();
  for(int p=t;p<LL*DD;p+=128) s_fn[p]*=s_inv[p>>7];
  __syncthreads();
  int lr=last_nodes[b]-b*LL; if(lr<0||lr>=LL) lr=LL-1;   // == L-1 by construction
  s_fl[t]=s_fn[lr*DD+t];
  __syncthreads();
  float fv;
  {
    float acc=fcv_b[t];
    const float* wv=fcv_w + t*DD;
    #pragma unroll 8
    for(int j=0;j<DD;j++) acc += s_fl[j]*wv[j];
    fv=acc;
  }
  const float fce=fce_w[t];
  const float* wu=fcu_w + t*DD;
  for(int n=0;n<LL;n++){
    float fu=0.f;
    #pragma unroll 8
    for(int j=0;j<DD;j++) fu += s_fn[n*DD+j]*wu[j];
    float sv = fce/(1.f+__expf(-(fu+fv)));   // sigmoid * fce_w[d]
    #pragma unroll
    for(int o=32;o>0;o>>=1) sv += __shfl_xor(sv,o,64);
    if((t&63)==0) s_red[t>>6]=sv;
    __syncthreads();
    if(t==0) s_e[n]=s_red[0]+s_red[1];
    __syncthreads();
  }
  if(t<64){ // softmax over the 20 session nodes
    float ev=(t<LL)? s_e[t] : -1e30f;
    float m=ev;
    #pragma unroll
    for(int o=32;o>0;o>>=1) m=fmaxf(m,__shfl_xor(m,o,64));
    float ex=(t<LL)? __expf(ev-m):0.f;
    float ssum=ex;
    #pragma unroll
    for(int o=32;o>0;o>>=1) ssum+=__shfl_xor(ssum,o,64);
    if(t<LL) s_alpha[t]=ex/ssum;
  }
  __syncthreads();
  float sg=0.f;
  for(int n=0;n<LL;n++) sg += s_alpha[n]*s_fn[n*DD+t];
  s_sg[t]=sg;
  __syncthreads();
  // sr = l2n([sr_l, sr_g] @ fcsr_w.T + te)
  float pre=te[(size_t)b*DD+t];
  const float* wsr=fcsr_w + t*2*DD;
  #pragma unroll 8
  for(int j=0;j<DD;j++) pre += s_fl[j]*wsr[j];
  #pragma unroll 8
  for(int j=0;j<DD;j++) pre += s_sg[j]*wsr[DD+j];
  float ss=pre*pre;
  #pragma unroll
  for(int o=32;o>0;o>>=1) ss+=__shfl_xor(ss,o,64);
  if((t&63)==0) s_red[t>>6]=ss;
  __syncthreads();
  float tot=s_red[0]+s_red[1];
  sr[(size_t)b*DD+t]=pre/(sqrtf(tot)+1e-12f);
}

// ================= K3: logits (f32 out), inline emb-row norm ===============
__global__ __launch_bounds__(256) void k_logits(
    const float* __restrict__ emb, const float* __restrict__ srr,
    float* __restrict__ out){
  const int v=blockIdx.x*256+threadIdx.x;
  if(v>=VN) return;
  const int bstart=blockIdx.y*256;
  float er[DD];
  {
    const float4* ev=(const float4*)emb + (size_t)v*32;
    #pragma unroll
    for(int j=0;j<32;j++){
      float4 u=ev[j];
      er[j*4+0]=u.x; er[j*4+1]=u.y; er[j*4+2]=u.z; er[j*4+3]=u.w;
    }
  }
  float nrm=0.f;
  #pragma unroll
  for(int d=0;d<DD;d++) nrm += er[d]*er[d];
  const float rn=12.f/(sqrtf(nrm)+1e-12f);
  for(int b=bstart;b<bstart+256;b++){
    const float* s=srr+(size_t)b*DD;        // wave-uniform -> scalar loads
    float acc=0.f;
    #pragma unroll
    for(int d=0;d<DD;d++) acc += er[d]*s[d];
    out[(size_t)b*VN+v]=acc*rn;
  }
}

// ================= K4: per-row logsumexp over V (online, f32) ==============
__global__ __launch_bounds__(256) void k_lse(const float* __restrict__ out,
                                             float* __restrict__ lse){
  const int b=blockIdx.x, t=threadIdx.x;
  const float4* rp=(const float4*)(out + (size_t)b*VN);
  float m=-1e30f, s=0.f;
  for(int i=t;i<VN/4;i+=256){
    float4 x=rp[i];
    float mx=fmaxf(fmaxf(x.x,x.y),fmaxf(x.z,x.w));
    if(mx>m){ s=s*__expf(m-mx); m=mx; }
    s += __expf(x.x-m)+__expf(x.y-m)+__expf(x.z-m)+__expf(x.w-m);
  }
  __shared__ float sm[256], ssb[256];
  sm[t]=m; ssb[t]=s;
  __syncthreads();
  for(int o=128;o>0;o>>=1){
    if(t<o){
      float m1=sm[t], m2=sm[t+o], s1=ssb[t], s2=ssb[t+o];
      float mm=fmaxf(m1,m2);
      sm[t]=mm; ssb[t]=s1*__expf(m1-mm)+s2*__expf(m2-mm);
    }
    __syncthreads();
  }
  if(t==0) lse[b]=sm[0]+logf(ssb[0]);
}

// ================= K5: out -= lse[b] (in place, float4) ====================
__global__ __launch_bounds__(256) void k_sub(float* __restrict__ out,
                                             const float* __restrict__ lse){
  const size_t i=(size_t)blockIdx.x*256+threadIdx.x;  // float4 index
  const int b=(int)((i*4)/VN);                         // VN%4==0: no row cross
  const float l=lse[b];
  float4* p=(float4*)out;
  float4 x=p[i];
  x.x-=l; x.y-=l; x.z-=l; x.w-=l;
  p[i]=x;
}

extern "C" void kernel_launch(void* const* d_in, const int* in_sizes, int n_in,
                              void* d_out, int out_size, void* d_ws, size_t ws_size,
                              hipStream_t stream){
  const float* emb    = (const float*)d_in[0];
  // d_in[1..6]: W1,W2,gru_* — dead code in the reference, never read
  const float* fcu_w  = (const float*)d_in[7];
  const float* fcv_w  = (const float*)d_in[8];
  const float* fcv_b  = (const float*)d_in[9];
  const float* fce_w  = (const float*)d_in[10];
  const float* fcsr_w = (const float*)d_in[11];
  const float* red_w  = (const float*)d_in[12];
  const float* red_b  = (const float*)d_in[13];
  const float* rec_w  = (const float*)d_in[14];
  const float* rec_b  = (const float*)d_in[15];
  const float* cde_w1 = (const float*)d_in[16];
  const float* cde_b1 = (const float*)d_in[17];
  const float* cde_w2 = (const float*)d_in[18];
  const float* cde_b2 = (const float*)d_in[19];
  const float* init_w = (const float*)d_in[20];
  const float* init_b = (const float*)d_in[21];
  // d_in[22]: w (edge weights) — dead code
  const float* times  = (const float*)d_in[23];
  const int* iid    = (const int*)d_in[24];
  // d_in[25..27]: src,dst,seg_ids — dead / implied by layout
  const int* last_nodes = (const int*)d_in[28];
  const int* embeds_ids = (const int*)d_in[29];
  float* out = (float*)d_out;

  float* ws  = (float*)d_ws;
  float* te  = ws;                    // B*D = 65,536 f
  float* sr  = te + (size_t)BB*DD;    // B*D = 65,536 f
  float* lse = sr + (size_t)BB*DD;    // B   =     512 f   (total 526 KB)

  k_cde   <<<BB/4, 256, 0, stream>>>(emb, embeds_ids, times, red_w, red_b,
                                     cde_w1, cde_b1, cde_w2, cde_b2,
                                     init_w, init_b, rec_w, rec_b, te);
  k_attn  <<<BB, 128, 0, stream>>>(emb, iid, last_nodes, fcu_w, fcv_w, fcv_b,
                                   fce_w, fcsr_w, te, sr);
  k_logits<<<dim3((VN+255)/256, 2), 256, 0, stream>>>(emb, sr, out);
  k_lse   <<<BB, 256, 0, stream>>>(out, lse);
  k_sub   <<<(int)(((size_t)BB*VN/4+255)/256), 256, 0, stream>>>(out, lse);
}